// Round 1
// baseline (261.091 us; speedup 1.0000x reference)
//
#include <hip/hip_runtime.h>

typedef __attribute__((ext_vector_type(8))) short short8;
typedef __attribute__((ext_vector_type(4))) float float4v;
typedef __attribute__((ext_vector_type(4))) int int4v;

#define E_EDGES 300000
#define EPB 128                                 // edges per block (32 per wave)
#define NBLK ((E_EDGES + EPB - 1) / EPB)        // 2344 blocks per edge type
#define TAB_ELEMS 12800000                      // 100000 nodes x 128 feats

__device__ __forceinline__ short f2bf(float f) {
    unsigned u = __float_as_uint(f);
    return (short)((u + 0x7FFFu + ((u >> 16) & 1u)) >> 16);
}
__device__ __forceinline__ unsigned pk_bf16(float a, float b) {
    unsigned ua = __float_as_uint(a), ub = __float_as_uint(b);
    ua += 0x7FFFu + ((ua >> 16) & 1u);
    ub += 0x7FFFu + ((ub >> 16) & 1u);
    return __builtin_amdgcn_perm(ub, ua, 0x07060302);
}
__device__ __forceinline__ void cp16(const void* g, void* l) {
    __builtin_amdgcn_global_load_lds(
        (const __attribute__((address_space(1))) unsigned int*)g,
        (__attribute__((address_space(3))) unsigned int*)l, 16, 0, 0);
}

// ws layout (shorts):
//   [0..98304)            weight tiles [n][k] in 64-k tiles, chunk-XOR swizzled
//   [98304..+12.8M)       user_emb bf16
//   [..+25.6M)            item_emb bf16
// One fused prep kernel: blockIdx.x < 1024 -> table cvt chunk; >= 1024 -> weight tile.
__global__ void prep_all(const float* __restrict__ ue, const float* __restrict__ ie,
                         const float* __restrict__ Wbi_ui, const float* __restrict__ W1_ui,
                         const float* __restrict__ Wbi_iu, const float* __restrict__ W1_iu,
                         short* __restrict__ ws) {
    __shared__ short tr[64 * 68];
    const int t = blockIdx.y;
    const int tid = threadIdx.x;
    if (blockIdx.x < 1024) {                    // ---- streaming table conversion ----
        const float* src = t ? ie : ue;
        short* dst = ws + 98304 + (size_t)t * TAB_ELEMS;
        const int stride = 1024 * 256;
        for (int g = blockIdx.x * 256 + tid; g < TAB_ELEMS / 8; g += stride) {
            const float* p = src + (size_t)g * 8;
            float4v v0 = ((const float4v*)p)[0];
            float4v v1 = ((const float4v*)p)[1];
            int4v w = { (int)pk_bf16(v0[0], v0[1]), (int)pk_bf16(v0[2], v0[3]),
                        (int)pk_bf16(v1[0], v1[1]), (int)pk_bf16(v1[2], v1[3]) };
            *(int4v*)(dst + (size_t)g * 8) = w;
        }
        return;
    }
    // ---- weight transpose + swizzle (12 tiles per type) ----
    const int m = blockIdx.x - 1024;            // 0..11
    const float* W; int k0, n0, obase;
    if (m < 8) {                                // Wbi (K=256, N=128)
        int kt = m >> 1, nh = m & 1;
        W = t ? Wbi_iu : Wbi_ui; k0 = kt * 64; n0 = nh * 64;
        obase = t * 32768 + kt * 8192;
    } else {                                    // W1 (K=128, N=128)
        int mm = m - 8; int kt = mm >> 1, nh = mm & 1;
        W = t ? W1_iu : W1_ui; k0 = kt * 64; n0 = nh * 64;
        obase = 65536 + t * 16384 + kt * 8192;
    }
    for (int it = 0; it < 16; ++it) {
        int flat = it * 256 + tid;
        int kk = flat >> 6, nn = flat & 63;
        tr[nn * 68 + kk] = f2bf(W[(size_t)(k0 + kk) * 128 + n0 + nn]);
    }
    __syncthreads();
    for (int it = 0; it < 16; ++it) {
        int flat = it * 256 + tid;
        int nn = flat >> 6, kk = flat & 63;
        int n = n0 + nn;
        ws[obase + n * 64 + (kk ^ ((n & 7) << 3))] = tr[nn * 68 + kk];
    }
}

// LDS budget: 2 x 16 KiB weight buffers = 32768 B -> 4 blocks/CU (was 51200 -> 3).
// H staging reuses the idle weight buffer (mt-sequential, 4 KB/wave, XOR-swizzled).
// K-loop is the T3-minimum 2-phase pipeline: STAGE(k+1) issued BEFORE compute(k),
// ONE barrier per tile -> DMA latency hides under the MFMA phase instead of
// sitting exposed between two barriers.
template<bool BF16G>
__launch_bounds__(256, 4)
__global__ void edge_decoder(
    const float* __restrict__ user_emb, const float* __restrict__ item_emb,
    const int* __restrict__ ei_ui, const int* __restrict__ ei_iu,
    const float* __restrict__ b_bi_ui, const float* __restrict__ b1_ui,
    const float* __restrict__ W2_ui, const float* __restrict__ b2_ui,
    const float* __restrict__ b_bi_iu, const float* __restrict__ b1_iu,
    const float* __restrict__ W2_iu, const float* __restrict__ b2_iu,
    const short* __restrict__ ws, const short* __restrict__ tab,
    float* __restrict__ out)
{
    __shared__ short Blds[2][128 * 64];         // 32768 B total (double buffer)

    const int type = blockIdx.y;
    const int e0 = blockIdx.x * EPB;
    const int tid = threadIdx.x;
    const int wave = tid >> 6, lane = tid & 63;
    const int q = lane >> 4, ln = lane & 15;

    const int*   ei   = type ? ei_iu : ei_ui;
    const float* bbi  = type ? b_bi_iu : b_bi_ui;
    const float* b1v  = type ? b1_iu : b1_ui;
    const float* W2v  = type ? W2_iu : W2_ui;
    const float* b2v  = type ? b2_iu : b2_ui;
    const short* WbiT = ws + type * 32768;
    const short* W1T  = ws + 65536 + type * 16384;

    // DMA weight tile 0 -> buf0 immediately (overlaps index load + gather)
    for (int c = 0; c < 4; ++c)
        cp16(WbiT + c * 2048 + tid * 8, &Blds[0][c * 2048 + tid * 8]);

    // two edges per lane (M-tiles mt=0,1)
    int si[2], di[2];
    for (int mt = 0; mt < 2; ++mt) {
        int erow = e0 + wave * 32 + mt * 16 + ln;
        int safe = (erow < E_EDGES) ? erow : 0;
        si[mt] = ei[safe];
        di[mt] = ei[E_EDGES + safe];
    }

    // gather A fragments: a[mt][ks] elem j = e_cat[edge][32*ks + 8*q + j]
    short8 a[2][8];
    if (BF16G) {
        for (int mt = 0; mt < 2; ++mt) {
            const short* sp = tab + (size_t)(type ? TAB_ELEMS : 0) + (size_t)si[mt] * 128;
            const short* dp = tab + (size_t)(type ? 0 : TAB_ELEMS) + (size_t)di[mt] * 128;
            for (int ks = 0; ks < 4; ++ks)
                a[mt][ks] = *(const short8*)(sp + ks * 32 + q * 8);
            for (int ks = 4; ks < 8; ++ks)
                a[mt][ks] = *(const short8*)(dp + (ks - 4) * 32 + q * 8);
        }
    } else {
        const float* srcT = type ? item_emb : user_emb;
        const float* dstT = type ? user_emb : item_emb;
        for (int mt = 0; mt < 2; ++mt)
            for (int ks = 0; ks < 8; ++ks) {
                const float* p = (ks < 4) ? (srcT + (size_t)si[mt] * 128 + ks * 32 + q * 8)
                                          : (dstT + (size_t)di[mt] * 128 + (ks - 4) * 32 + q * 8);
                float4v v0 = ((const float4v*)p)[0];
                float4v v1 = ((const float4v*)p)[1];
                int4v w = { (int)pk_bf16(v0[0], v0[1]), (int)pk_bf16(v0[2], v0[3]),
                            (int)pk_bf16(v1[0], v1[1]), (int)pk_bf16(v1[2], v1[3]) };
                a[mt][ks] = *(short8*)&w;
            }
    }

    // acc init = bias (column-only -> all 4 row-elems identical)
    float4v acc[2][8];
    for (int nt = 0; nt < 8; ++nt) {
        float bb = bbi[nt * 16 + ln];
        acc[0][nt] = (float4v){bb, bb, bb, bb};
        acc[1][nt] = acc[0][nt];
    }

    const int swz = (ln & 7) << 3;

    // ---- Layer 1: K=256, 4 tiles of 64-K, double-buffered, 1 barrier/tile ----
    int cur = 0;
    for (int kt = 0; kt < 4; ++kt) {
        __syncthreads();                        // tile kt resident in buf[cur]
        const short* nxt = (kt < 3) ? (WbiT + (kt + 1) * 8192) : W1T;
        for (int c = 0; c < 4; ++c)             // stage k+1 BEFORE compute(k)
            cp16(nxt + c * 2048 + tid * 8, &Blds[cur ^ 1][c * 2048 + tid * 8]);
        __builtin_amdgcn_s_setprio(1);
        for (int ks2 = 0; ks2 < 2; ++ks2) {
            int ka = (ks2 * 32 + q * 8) ^ swz;
            int ks = kt * 2 + ks2;
            for (int nt = 0; nt < 8; ++nt) {
                short8 bf = *(const short8*)&Blds[cur][(nt * 16 + ln) * 64 + ka];
                acc[0][nt] = __builtin_amdgcn_mfma_f32_16x16x32_bf16(a[0][ks], bf, acc[0][nt], 0, 0, 0);
                acc[1][nt] = __builtin_amdgcn_mfma_f32_16x16x32_bf16(a[1][ks], bf, acc[1][nt], 0, 0, 0);
            }
        }
        __builtin_amdgcn_s_setprio(0);
        cur ^= 1;
    }

    __syncthreads();                            // W1 tile0 resident in buf[cur];
                                                // buf[cur^1] now free -> H staging

    // ---- Epilogue 1: ELU -> bf16 H, mt-sequential, in buf[cur^1] ----
    // Per-wave 2048-short region. XOR group swizzle: group g (8 shorts = 16B)
    // of row r stored at g ^ (r&7) -> read side (b128, fixed ks) is 2-way = free.
    short* Hw = &Blds[cur ^ 1][wave * 2048];
    short8 a2[2][4];
    for (int mt = 0; mt < 2; ++mt) {
        for (int nt = 0; nt < 8; ++nt) {
            float4v v = acc[mt][nt];
            for (int r = 0; r < 4; ++r) {
                float x = v[r];
                float h = x > 0.f ? x : (__expf(x) - 1.f);
                int row = q * 4 + r;
                int g = (nt * 2 + (ln >> 3)) ^ (row & 7);
                Hw[row * 128 + g * 8 + (ln & 7)] = f2bf(h);
            }
        }
        // same-wave LDS RAW; compiler inserts lgkmcnt wait
        for (int ks = 0; ks < 4; ++ks)
            a2[mt][ks] = *(const short8*)&Hw[ln * 128 + (((ks * 4 + q) ^ (ln & 7)) << 3)];
    }

    for (int nt = 0; nt < 8; ++nt) {
        float bb = b1v[nt * 16 + ln];
        acc[0][nt] = (float4v){bb, bb, bb, bb};
        acc[1][nt] = acc[0][nt];
    }

    __syncthreads();                            // all waves done reading H
    // stage W1 tile1 -> buf[cur^1]; overlaps tile0 compute
    for (int c = 0; c < 4; ++c)
        cp16(W1T + 8192 + c * 2048 + tid * 8, &Blds[cur ^ 1][c * 2048 + tid * 8]);

    // ---- Layer 2: K=128, 2 tiles of 64-K, pipelined ----
    for (int kt = 0; kt < 2; ++kt) {
        if (kt == 1) __syncthreads();           // tile1 resident
        __builtin_amdgcn_s_setprio(1);
        for (int ks2 = 0; ks2 < 2; ++ks2) {
            int ka = (ks2 * 32 + q * 8) ^ swz;
            int ks = kt * 2 + ks2;
            for (int nt = 0; nt < 8; ++nt) {
                short8 bf = *(const short8*)&Blds[cur][(nt * 16 + ln) * 64 + ka];
                acc[0][nt] = __builtin_amdgcn_mfma_f32_16x16x32_bf16(a2[0][ks], bf, acc[0][nt], 0, 0, 0);
                acc[1][nt] = __builtin_amdgcn_mfma_f32_16x16x32_bf16(a2[1][ks], bf, acc[1][nt], 0, 0, 0);
            }
        }
        __builtin_amdgcn_s_setprio(0);
        cur ^= 1;
    }

    // ---- Epilogue 2: ELU, dot W2, 16-lane reduce, sigmoid, store ----
    for (int mt = 0; mt < 2; ++mt) {
        float s0 = 0.f, s1 = 0.f, s2 = 0.f, s3 = 0.f;
        for (int nt = 0; nt < 8; ++nt) {
            float wv = W2v[nt * 16 + ln];
            float4v v = acc[mt][nt];
            float x;
            x = v[0]; x = x > 0.f ? x : (__expf(x) - 1.f); s0 += x * wv;
            x = v[1]; x = x > 0.f ? x : (__expf(x) - 1.f); s1 += x * wv;
            x = v[2]; x = x > 0.f ? x : (__expf(x) - 1.f); s2 += x * wv;
            x = v[3]; x = x > 0.f ? x : (__expf(x) - 1.f); s3 += x * wv;
        }
        for (int off = 1; off < 16; off <<= 1) {
            s0 += __shfl_xor(s0, off);
            s1 += __shfl_xor(s1, off);
            s2 += __shfl_xor(s2, off);
            s3 += __shfl_xor(s3, off);
        }
        if (ln < 4) {
            float sv = (ln == 0) ? s0 : (ln == 1) ? s1 : (ln == 2) ? s2 : s3;
            int e = e0 + wave * 32 + mt * 16 + q * 4 + ln;
            if (e < E_EDGES) {
                float z = sv + b2v[0];
                out[type * E_EDGES + e] = 1.f / (1.f + __expf(-z));
            }
        }
    }
}

extern "C" void kernel_launch(void* const* d_in, const int* in_sizes, int n_in,
                              void* d_out, int out_size, void* d_ws, size_t ws_size,
                              hipStream_t stream) {
    const float* user_emb = (const float*)d_in[0];
    const float* item_emb = (const float*)d_in[1];
    const int*   ei_ui    = (const int*)d_in[2];
    const int*   ei_iu    = (const int*)d_in[3];
    const float* W_bi_ui  = (const float*)d_in[4];
    const float* b_bi_ui  = (const float*)d_in[5];
    const float* W1_ui    = (const float*)d_in[6];
    const float* b1_ui    = (const float*)d_in[7];
    const float* W2_ui    = (const float*)d_in[8];
    const float* b2_ui    = (const float*)d_in[9];
    const float* W_bi_iu  = (const float*)d_in[10];
    const float* b_bi_iu  = (const float*)d_in[11];
    const float* W1_iu    = (const float*)d_in[12];
    const float* b1_iu    = (const float*)d_in[13];
    const float* W2_iu    = (const float*)d_in[14];
    const float* b2_iu    = (const float*)d_in[15];
    short* ws  = (short*)d_ws;
    short* tab = ws + 98304;
    float* out = (float*)d_out;

    const size_t need = 98304u * 2u + (size_t)2 * TAB_ELEMS * 2u;  // 51.4 MB

    if (ws_size >= need) {
        hipLaunchKernelGGL(prep_all, dim3(1036, 2), dim3(256), 0, stream,
                           user_emb, item_emb, W_bi_ui, W1_ui, W_bi_iu, W1_iu, ws);
        edge_decoder<true><<<dim3(NBLK, 2), dim3(256), 0, stream>>>(
            user_emb, item_emb, ei_ui, ei_iu,
            b_bi_ui, b1_ui, W2_ui, b2_ui,
            b_bi_iu, b1_iu, W2_iu, b2_iu,
            ws, tab, out);
    } else {
        hipLaunchKernelGGL(prep_all, dim3(1036, 2), dim3(256), 0, stream,
                           user_emb, item_emb, W_bi_ui, W1_ui, W_bi_iu, W1_iu, ws);
        edge_decoder<false><<<dim3(NBLK, 2), dim3(256), 0, stream>>>(
            user_emb, item_emb, ei_ui, ei_iu,
            b_bi_ui, b1_ui, W2_ui, b2_ui,
            b_bi_iu, b1_iu, W2_iu, b2_iu,
            ws, tab, out);
    }
}

// Round 2
// 237.423 us; speedup vs baseline: 1.0997x; 1.0997x over previous
//
#include <hip/hip_runtime.h>

typedef __attribute__((ext_vector_type(8))) short short8;
typedef __attribute__((ext_vector_type(4))) float float4v;
typedef __attribute__((ext_vector_type(4))) int int4v;

#define E_EDGES 300000
#define EPB 128                                 // edges per block (32 per wave)
#define NBLK ((E_EDGES + EPB - 1) / EPB)        // 2344 blocks per edge type
#define TAB_ELEMS 12800000                      // 100000 nodes x 128 feats

__device__ __forceinline__ short f2bf(float f) {
    unsigned u = __float_as_uint(f);
    return (short)((u + 0x7FFFu + ((u >> 16) & 1u)) >> 16);
}
__device__ __forceinline__ unsigned pk_bf16(float a, float b) {
    unsigned ua = __float_as_uint(a), ub = __float_as_uint(b);
    ua += 0x7FFFu + ((ua >> 16) & 1u);
    ub += 0x7FFFu + ((ub >> 16) & 1u);
    return __builtin_amdgcn_perm(ub, ua, 0x07060302);
}
__device__ __forceinline__ void cp16(const void* g, void* l) {
    __builtin_amdgcn_global_load_lds(
        (const __attribute__((address_space(1))) unsigned int*)g,
        (__attribute__((address_space(3))) unsigned int*)l, 16, 0, 0);
}

// ws layout (shorts):
//   [0..98304)            weight tiles [n][k] in 64-k tiles, chunk-XOR swizzled
//   [98304..+12.8M)       user_emb bf16
//   [..+25.6M)            item_emb bf16
__global__ void prep_all(const float* __restrict__ ue, const float* __restrict__ ie,
                         const float* __restrict__ Wbi_ui, const float* __restrict__ W1_ui,
                         const float* __restrict__ Wbi_iu, const float* __restrict__ W1_iu,
                         short* __restrict__ ws) {
    __shared__ short tr[64 * 68];
    const int t = blockIdx.y;
    const int tid = threadIdx.x;
    if (blockIdx.x < 1024) {                    // ---- streaming table conversion ----
        const float* src = t ? ie : ue;
        short* dst = ws + 98304 + (size_t)t * TAB_ELEMS;
        const int stride = 1024 * 256;
        for (int g = blockIdx.x * 256 + tid; g < TAB_ELEMS / 8; g += stride) {
            const float* p = src + (size_t)g * 8;
            float4v v0 = ((const float4v*)p)[0];
            float4v v1 = ((const float4v*)p)[1];
            int4v w = { (int)pk_bf16(v0[0], v0[1]), (int)pk_bf16(v0[2], v0[3]),
                        (int)pk_bf16(v1[0], v1[1]), (int)pk_bf16(v1[2], v1[3]) };
            *(int4v*)(dst + (size_t)g * 8) = w;
        }
        return;
    }
    // ---- weight transpose + swizzle (12 tiles per type) ----
    const int m = blockIdx.x - 1024;            // 0..11
    const float* W; int k0, n0, obase;
    if (m < 8) {                                // Wbi (K=256, N=128)
        int kt = m >> 1, nh = m & 1;
        W = t ? Wbi_iu : Wbi_ui; k0 = kt * 64; n0 = nh * 64;
        obase = t * 32768 + kt * 8192;
    } else {                                    // W1 (K=128, N=128)
        int mm = m - 8; int kt = mm >> 1, nh = mm & 1;
        W = t ? W1_iu : W1_ui; k0 = kt * 64; n0 = nh * 64;
        obase = 65536 + t * 16384 + kt * 8192;
    }
    for (int it = 0; it < 16; ++it) {
        int flat = it * 256 + tid;
        int kk = flat >> 6, nn = flat & 63;
        tr[nn * 68 + kk] = f2bf(W[(size_t)(k0 + kk) * 128 + n0 + nn]);
    }
    __syncthreads();
    for (int it = 0; it < 16; ++it) {
        int flat = it * 256 + tid;
        int nn = flat >> 6, kk = flat & 63;
        int n = n0 + nn;
        ws[obase + n * 64 + (kk ^ ((n & 7) << 3))] = tr[nn * 68 + kk];
    }
}

// Register budget: __launch_bounds__(256,4) caps at 128 regs/thread (4 blocks/CU).
// acc = 64; A lives in TWO ping-pong per-tile buffers (aA/aB, 16 regs each) gathered
// per K-tile instead of 64 regs upfront -> ~120 total, no scratch (round-1's 100 MB
// WRITE_SIZE was a[] spilling under the 128 cap).
// All K-loops hand-unrolled via macros: every array index is compile-time (rule #20).
// Pipeline: 1 barrier/tile; weight DMA(k+1) + A-gather(k+2) issued under compute(k).
template<bool BF16G>
__launch_bounds__(256, 4)
__global__ void edge_decoder(
    const float* __restrict__ user_emb, const float* __restrict__ item_emb,
    const int* __restrict__ ei_ui, const int* __restrict__ ei_iu,
    const float* __restrict__ b_bi_ui, const float* __restrict__ b1_ui,
    const float* __restrict__ W2_ui, const float* __restrict__ b2_ui,
    const float* __restrict__ b_bi_iu, const float* __restrict__ b1_iu,
    const float* __restrict__ W2_iu, const float* __restrict__ b2_iu,
    const short* __restrict__ ws, const short* __restrict__ tab,
    float* __restrict__ out)
{
    __shared__ short Blds[2][128 * 64];         // 32768 B total (double buffer)

    const int type = blockIdx.y;
    const int e0 = blockIdx.x * EPB;
    const int tid = threadIdx.x;
    const int wave = tid >> 6, lane = tid & 63;
    const int q = lane >> 4, ln = lane & 15;

    const int*   ei   = type ? ei_iu : ei_ui;
    const float* bbi  = type ? b_bi_iu : b_bi_ui;
    const float* b1v  = type ? b1_iu : b1_ui;
    const float* W2v  = type ? W2_iu : W2_ui;
    const float* b2v  = type ? b2_iu : b2_ui;
    const short* WbiT = ws + type * 32768;
    const short* W1T  = ws + 65536 + type * 16384;

    // DMA weight tile 0 -> buf0 immediately (overlaps index load + gather t0/t1)
    #pragma unroll
    for (int c = 0; c < 4; ++c)
        cp16(WbiT + c * 2048 + tid * 8, &Blds[0][c * 2048 + tid * 8]);

    // two edges per lane (M-tiles mt=0,1)
    int si[2], di[2];
    #pragma unroll
    for (int mt = 0; mt < 2; ++mt) {
        int erow = e0 + wave * 32 + mt * 16 + ln;
        int safe = (erow < E_EDGES) ? erow : 0;
        si[mt] = ei[safe];
        di[mt] = ei[E_EDGES + safe];
    }

    // per-edge row pointers (already offset by q*8 within the row)
    const short* sp[2]; const short* dp[2];     // bf16-table path
    const float* spf[2]; const float* dpf[2];   // fp32 fallback path
    if (BF16G) {
        #pragma unroll
        for (int mt = 0; mt < 2; ++mt) {
            sp[mt] = tab + (size_t)(type ? TAB_ELEMS : 0) + (size_t)si[mt] * 128 + q * 8;
            dp[mt] = tab + (size_t)(type ? 0 : TAB_ELEMS) + (size_t)di[mt] * 128 + q * 8;
        }
    } else {
        const float* srcT = type ? item_emb : user_emb;
        const float* dstT = type ? user_emb : item_emb;
        #pragma unroll
        for (int mt = 0; mt < 2; ++mt) {
            spf[mt] = srcT + (size_t)si[mt] * 128 + q * 8;
            dpf[mt] = dstT + (size_t)di[mt] * 128 + q * 8;
        }
    }

    short8 aA[2][2], aB[2][2];                  // ping-pong per-tile A fragments

// Gather one K-tile of A into BUF. HALF: 0 = src row, 1 = dst row.
// OFF: element offset within the 128-elem row (0 or 64).
#define GATHER(BUF, HALF, OFF) do { \
    _Pragma("unroll") \
    for (int mt = 0; mt < 2; ++mt) { \
        _Pragma("unroll") \
        for (int k2 = 0; k2 < 2; ++k2) { \
            if (BF16G) { \
                BUF[mt][k2] = *(const short8*)((HALF ? dp[mt] : sp[mt]) + OFF + k2 * 32); \
            } else { \
                const float* p = (HALF ? dpf[mt] : spf[mt]) + OFF + k2 * 32; \
                float4v v0 = ((const float4v*)p)[0]; \
                float4v v1 = ((const float4v*)p)[1]; \
                int4v w = { (int)pk_bf16(v0[0], v0[1]), (int)pk_bf16(v0[2], v0[3]), \
                            (int)pk_bf16(v1[0], v1[1]), (int)pk_bf16(v1[2], v1[3]) }; \
                BUF[mt][k2] = *(short8*)&w; \
            } \
        } \
    } } while (0)

    GATHER(aA, 0, 0);                           // tile 0: src[0:64)
    GATHER(aB, 0, 64);                          // tile 1: src[64:128)

    // acc init = bias (column-only -> all 4 row-elems identical)
    float4v acc[2][8];
    #pragma unroll
    for (int nt = 0; nt < 8; ++nt) {
        float bb = bbi[nt * 16 + ln];
        acc[0][nt] = (float4v){bb, bb, bb, bb};
        acc[1][nt] = acc[0][nt];
    }

    const int swz = (ln & 7) << 3;

// One layer-1 K-tile: barrier (tile KT resident in buf[KT&1]), stage weight
// tile KT+1 into buf[(KT+1)&1], then 16 MFMA from ABUF. KT is a macro literal.
#define L1_TILE(KT, ABUF) do { \
    __syncthreads(); \
    const short* nxt = (KT < 3) ? (WbiT + (KT + 1) * 8192) : W1T; \
    _Pragma("unroll") \
    for (int c = 0; c < 4; ++c) \
        cp16(nxt + c * 2048 + tid * 8, &Blds[(KT + 1) & 1][c * 2048 + tid * 8]); \
    __builtin_amdgcn_s_setprio(1); \
    _Pragma("unroll") \
    for (int ks2 = 0; ks2 < 2; ++ks2) { \
        int ka = (ks2 * 32 + q * 8) ^ swz; \
        _Pragma("unroll") \
        for (int nt = 0; nt < 8; ++nt) { \
            short8 bf = *(const short8*)&Blds[KT & 1][(nt * 16 + ln) * 64 + ka]; \
            acc[0][nt] = __builtin_amdgcn_mfma_f32_16x16x32_bf16(ABUF[0][ks2], bf, acc[0][nt], 0, 0, 0); \
            acc[1][nt] = __builtin_amdgcn_mfma_f32_16x16x32_bf16(ABUF[1][ks2], bf, acc[1][nt], 0, 0, 0); \
        } \
    } \
    __builtin_amdgcn_s_setprio(0); \
    } while (0)

    // ---- Layer 1: K=256 concat [src|dst], 4 tiles of 64-K ----
    L1_TILE(0, aA);
    GATHER(aA, 1, 0);                           // tile 2: dst[0:64)  (aA just freed)
    L1_TILE(1, aB);
    GATHER(aB, 1, 64);                          // tile 3: dst[64:128) (aB just freed)
    L1_TILE(2, aA);
    L1_TILE(3, aB);                             // stages W1 tile0 -> buf0

    __syncthreads();                            // W1t0 resident; buf1 free -> H staging

    // ---- Epilogue 1: ELU -> bf16 H, mt-sequential, per-wave region of buf1 ----
    // XOR group swizzle: 16B group g of row r stored at g ^ (r&7); read side is
    // 2-way (free). Same-wave LDS RAW; compiler inserts lgkmcnt wait.
    short* Hw = &Blds[1][wave * 2048];
    short8 a2[2][4];
    #pragma unroll
    for (int mt = 0; mt < 2; ++mt) {
        #pragma unroll
        for (int nt = 0; nt < 8; ++nt) {
            float4v v = acc[mt][nt];
            #pragma unroll
            for (int r = 0; r < 4; ++r) {
                float x = v[r];
                float h = x > 0.f ? x : (__expf(x) - 1.f);
                int row = q * 4 + r;
                int g = (nt * 2 + (ln >> 3)) ^ (row & 7);
                Hw[row * 128 + g * 8 + (ln & 7)] = f2bf(h);
            }
        }
        #pragma unroll
        for (int ks = 0; ks < 4; ++ks)
            a2[mt][ks] = *(const short8*)&Hw[ln * 128 + (((ks * 4 + q) ^ (ln & 7)) << 3)];
    }

    #pragma unroll
    for (int nt = 0; nt < 8; ++nt) {
        float bb = b1v[nt * 16 + ln];
        acc[0][nt] = (float4v){bb, bb, bb, bb};
        acc[1][nt] = acc[0][nt];
    }

    __syncthreads();                            // all waves done reading their H
    #pragma unroll
    for (int c = 0; c < 4; ++c)                 // stage W1 tile1 -> buf1 (under L2 t0)
        cp16(W1T + 8192 + c * 2048 + tid * 8, &Blds[1][c * 2048 + tid * 8]);

// One layer-2 K-tile from buf[KT]; A from a2 with compile-time index.
#define L2_TILE(KT) do { \
    if (KT == 1) __syncthreads(); \
    __builtin_amdgcn_s_setprio(1); \
    _Pragma("unroll") \
    for (int ks2 = 0; ks2 < 2; ++ks2) { \
        int ka = (ks2 * 32 + q * 8) ^ swz; \
        _Pragma("unroll") \
        for (int nt = 0; nt < 8; ++nt) { \
            short8 bf = *(const short8*)&Blds[KT][(nt * 16 + ln) * 64 + ka]; \
            acc[0][nt] = __builtin_amdgcn_mfma_f32_16x16x32_bf16(a2[0][KT * 2 + ks2], bf, acc[0][nt], 0, 0, 0); \
            acc[1][nt] = __builtin_amdgcn_mfma_f32_16x16x32_bf16(a2[1][KT * 2 + ks2], bf, acc[1][nt], 0, 0, 0); \
        } \
    } \
    __builtin_amdgcn_s_setprio(0); \
    } while (0)

    // ---- Layer 2: K=128, 2 tiles ----
    L2_TILE(0);
    L2_TILE(1);

    // ---- Epilogue 2: ELU, dot W2, 16-lane reduce, sigmoid, store ----
    #pragma unroll
    for (int mt = 0; mt < 2; ++mt) {
        float s0 = 0.f, s1 = 0.f, s2 = 0.f, s3 = 0.f;
        #pragma unroll
        for (int nt = 0; nt < 8; ++nt) {
            float wv = W2v[nt * 16 + ln];
            float4v v = acc[mt][nt];
            float x;
            x = v[0]; x = x > 0.f ? x : (__expf(x) - 1.f); s0 += x * wv;
            x = v[1]; x = x > 0.f ? x : (__expf(x) - 1.f); s1 += x * wv;
            x = v[2]; x = x > 0.f ? x : (__expf(x) - 1.f); s2 += x * wv;
            x = v[3]; x = x > 0.f ? x : (__expf(x) - 1.f); s3 += x * wv;
        }
        for (int off = 1; off < 16; off <<= 1) {
            s0 += __shfl_xor(s0, off);
            s1 += __shfl_xor(s1, off);
            s2 += __shfl_xor(s2, off);
            s3 += __shfl_xor(s3, off);
        }
        if (ln < 4) {
            float sv = (ln == 0) ? s0 : (ln == 1) ? s1 : (ln == 2) ? s2 : s3;
            int e = e0 + wave * 32 + mt * 16 + q * 4 + ln;
            if (e < E_EDGES) {
                float z = sv + b2v[0];
                out[type * E_EDGES + e] = 1.f / (1.f + __expf(-z));
            }
        }
    }
#undef GATHER
#undef L1_TILE
#undef L2_TILE
}

extern "C" void kernel_launch(void* const* d_in, const int* in_sizes, int n_in,
                              void* d_out, int out_size, void* d_ws, size_t ws_size,
                              hipStream_t stream) {
    const float* user_emb = (const float*)d_in[0];
    const float* item_emb = (const float*)d_in[1];
    const int*   ei_ui    = (const int*)d_in[2];
    const int*   ei_iu    = (const int*)d_in[3];
    const float* W_bi_ui  = (const float*)d_in[4];
    const float* b_bi_ui  = (const float*)d_in[5];
    const float* W1_ui    = (const float*)d_in[6];
    const float* b1_ui    = (const float*)d_in[7];
    const float* W2_ui    = (const float*)d_in[8];
    const float* b2_ui    = (const float*)d_in[9];
    const float* W_bi_iu  = (const float*)d_in[10];
    const float* b_bi_iu  = (const float*)d_in[11];
    const float* W1_iu    = (const float*)d_in[12];
    const float* b1_iu    = (const float*)d_in[13];
    const float* W2_iu    = (const float*)d_in[14];
    const float* b2_iu    = (const float*)d_in[15];
    short* ws  = (short*)d_ws;
    short* tab = ws + 98304;
    float* out = (float*)d_out;

    const size_t need = 98304u * 2u + (size_t)2 * TAB_ELEMS * 2u;  // 51.4 MB

    if (ws_size >= need) {
        hipLaunchKernelGGL(prep_all, dim3(1036, 2), dim3(256), 0, stream,
                           user_emb, item_emb, W_bi_ui, W1_ui, W_bi_iu, W1_iu, ws);
        edge_decoder<true><<<dim3(NBLK, 2), dim3(256), 0, stream>>>(
            user_emb, item_emb, ei_ui, ei_iu,
            b_bi_ui, b1_ui, W2_ui, b2_ui,
            b_bi_iu, b1_iu, W2_iu, b2_iu,
            ws, tab, out);
    } else {
        hipLaunchKernelGGL(prep_all, dim3(1036, 2), dim3(256), 0, stream,
                           user_emb, item_emb, W_bi_ui, W1_ui, W_bi_iu, W1_iu, ws);
        edge_decoder<false><<<dim3(NBLK, 2), dim3(256), 0, stream>>>(
            user_emb, item_emb, ei_ui, ei_iu,
            b_bi_ui, b1_ui, W2_ui, b2_ui,
            b_bi_iu, b1_iu, W2_iu, b2_iu,
            ws, tab, out);
    }
}